// Round 15
// baseline (157.860 us; speedup 1.0000x reference)
//
#include <hip/hip_runtime.h>

#define NN 100000
#define CSH 7                        // 128 nodes per bucket
#define CNODES 128
#define NC ((NN + CNODES - 1) / CNODES)      // 782 buckets
#define TPBS 512                     // block size
#define EPQ 4                        // int4 loads per thread in phase 1
#define TILE4 (TPBS * EPQ)           // 2048 int4 = 8192 edges per tile
#define TILEE (TILE4 * 4)            // 8192
#define PADG 16u                     // pad runs to 16 edges = 64 B line
#define SEGMAXP 7168                 // padded per-bucket capacity (mean ~6500, ~10 sigma)
#define SEGMAXP4 (SEGMAXP / 4)
#define ITK 4                        // uint4 items per thread in bucket phase
#define SENT 0xFFFFFFFFu

// ---- bf16 pack/unpack helpers (RNE) ----
__device__ __forceinline__ unsigned f2bf(float f) {
    unsigned u = __float_as_uint(f);
    return (u + 0x7FFFu + ((u >> 16) & 1u)) >> 16;
}
__device__ __forceinline__ unsigned pk(float lo, float hi) {
    return f2bf(lo) | (f2bf(hi) << 16);
}
__device__ __forceinline__ float bflo(unsigned v) { return __uint_as_float(v << 16); }
__device__ __forceinline__ float bfhi(unsigned v) { return __uint_as_float(v & 0xFFFF0000u); }

// FUSED persistent kernel.
// Phase 1 (per 8192-edge tile): q-pack slice + LDS multisplit (hist ->
//   hierarchical scan -> rank-scatter into LDS stage) -> write-combined flush
//   of 16-edge-padded per-bucket runs (full 16 B stores, pad = SENT).
// Device-scope spin barrier (all blocks resident: 45.4 KB LDS -> 3 blocks/CU,
//   768 slots >= 391 blocks; release/acquire threadfence for cross-XCD L2).
// Phase 2 (grid-stride over 782 buckets): single uint4 segment read into
//   registers; per-wave split histogram; one-pass cursors; register-sourced
//   placement into 16 B-aligned runs (slack = dummy col NN -> q=0); 4-lane
//   quad-per-node gather; finalize ||cnt*q - sum||^2/max(cnt,1)^2 -> out.
__global__ __launch_bounds__(TPBS) void k_fused(const float4* __restrict__ pred,
                        const float4* __restrict__ inp, uint4* __restrict__ qb,
                        const int4* __restrict__ row4, const int4* __restrict__ col4,
                        const int* __restrict__ row, const int* __restrict__ col,
                        unsigned* __restrict__ cursor, unsigned* __restrict__ binned,
                        unsigned* __restrict__ done, float* __restrict__ out,
                        int E, int n8, int N) {
    __shared__ unsigned shA[TILEE];          // 32 KB: stage (ph1) / scol (ph2)
    __shared__ unsigned shB[4 * NC];         // 12.5 KB: lcnt,lofs,lpos,gdst / ncnt8,ncnt,nstart
    __shared__ unsigned wtot[8], wofs[8];
    __shared__ float wred[8];
    int tid = threadIdx.x;
    int lane = tid & 63, wid = tid >> 6;

    // ---------------- phase 1: tile multisplit ----------------
    {
        unsigned* lcnt = shB;
        unsigned* lofs = shB + NC;
        unsigned* lpos = shB + 2 * NC;
        unsigned* gdst = shB + 3 * NC;
        unsigned* stage = shA;
        int E4 = E >> 2;
        long long base4 = (long long)blockIdx.x * TILE4;
        bool lastblk = (blockIdx.x == gridDim.x - 1);

        if (blockIdx.x == 0 && tid == 0) {   // out + dummy-q init (pre-barrier)
            *out = 0.f;
            qb[2 * NN]     = make_uint4(0u, 0u, 0u, 0u);
            qb[2 * NN + 1] = make_uint4(0u, 0u, 0u, 0u);
        }
        // fused q-pack: this block's slice
        for (int i = blockIdx.x * TPBS + tid; i < n8; i += gridDim.x * TPBS) {
            float4 a0 = pred[2 * i], a1 = pred[2 * i + 1];
            float4 b0 = inp[2 * i],  b1 = inp[2 * i + 1];
            uint4 o;
            o.x = pk(a0.x - b0.x, a0.y - b0.y);
            o.y = pk(a0.z - b0.z, a0.w - b0.w);
            o.z = pk(a1.x - b1.x, a1.y - b1.y);
            o.w = pk(a1.z - b1.z, a1.w - b1.w);
            qb[i] = o;
        }
        for (int i = tid; i < NC; i += TPBS) { lcnt[i] = 0u; lpos[i] = 0u; }
        __syncthreads();
        int4 r[EPQ], c[EPQ];
        bool val[EPQ];
        #pragma unroll
        for (int j = 0; j < EPQ; ++j) {
            long long i4 = base4 + (long long)j * TPBS + tid;
            val[j] = (i4 < E4);
            if (val[j]) {
                r[j] = row4[i4]; c[j] = col4[i4];
                atomicAdd(&lcnt[((unsigned)r[j].x) >> CSH], 1u);
                atomicAdd(&lcnt[((unsigned)r[j].y) >> CSH], 1u);
                atomicAdd(&lcnt[((unsigned)r[j].z) >> CSH], 1u);
                atomicAdd(&lcnt[((unsigned)r[j].w) >> CSH], 1u);
            }
        }
        int rt = 0, ct_ = 0;
        bool tval = lastblk && tid < (E & 3);
        if (tval) {
            int e = (E & ~3) + tid;
            rt = row[e]; ct_ = col[e];
            atomicAdd(&lcnt[((unsigned)rt) >> CSH], 1u);
        }
        __syncthreads();
        // hierarchical exclusive scan of lcnt (2 buckets per thread)
        unsigned v0 = (2 * tid     < NC) ? lcnt[2 * tid]     : 0u;
        unsigned v1 = (2 * tid + 1 < NC) ? lcnt[2 * tid + 1] : 0u;
        unsigned s = v0 + v1;
        unsigned x = s;
        #pragma unroll
        for (int off = 1; off < 64; off <<= 1) {
            unsigned t = __shfl_up(x, off);
            if (lane >= off) x += t;
        }
        if (lane == 63) wtot[wid] = x;
        __syncthreads();
        if (tid < 8) {
            unsigned wv = wtot[tid], wx = wv;
            #pragma unroll
            for (int off = 1; off < 8; off <<= 1) {
                unsigned t = __shfl_up(wx, off);
                if (tid >= off) wx += t;
            }
            wofs[tid] = wx - wv;
        }
        __syncthreads();
        unsigned ex = x - s + wofs[wid];
        if (2 * tid < NC) {
            lofs[2 * tid] = ex;
            unsigned rp = (v0 + PADG - 1u) & ~(PADG - 1u);
            gdst[2 * tid] = rp ? atomicAdd(&cursor[2 * tid], rp) : 0u;
        }
        if (2 * tid + 1 < NC) {
            lofs[2 * tid + 1] = ex + v0;
            unsigned rp = (v1 + PADG - 1u) & ~(PADG - 1u);
            gdst[2 * tid + 1] = rp ? atomicAdd(&cursor[2 * tid + 1], rp) : 0u;
        }
        __syncthreads();
        // rank-scatter payloads into LDS stage (contiguous per bucket)
        #pragma unroll
        for (int j = 0; j < EPQ; ++j) {
            if (val[j]) {
                int rr[4] = {r[j].x, r[j].y, r[j].z, r[j].w};
                int cc4[4] = {c[j].x, c[j].y, c[j].z, c[j].w};
                #pragma unroll
                for (int k = 0; k < 4; ++k) {
                    unsigned ru = (unsigned)rr[k];
                    unsigned b = ru >> CSH;
                    unsigned pos = lofs[b] + atomicAdd(&lpos[b], 1u);
                    stage[pos] = ((ru & (CNODES - 1u)) << 17) | (unsigned)cc4[k];
                }
            }
        }
        if (tval) {
            unsigned ru = (unsigned)rt;
            unsigned b = ru >> CSH;
            unsigned pos = lofs[b] + atomicAdd(&lpos[b], 1u);
            stage[pos] = ((ru & (CNODES - 1u)) << 17) | (unsigned)ct_;
        }
        __syncthreads();
        // flush: only full 16 B aligned stores; sentinel-pad to 16-edge boundary
        for (int i = tid; i < NC; i += TPBS) {
            unsigned cc = lcnt[i];
            unsigned rp = (cc + PADG - 1u) & ~(PADG - 1u);
            unsigned ls = lofs[i];
            unsigned gd = gdst[i];
            if (gd + rp > SEGMAXP) rp = (gd < SEGMAXP) ? (SEGMAXP - gd) : 0u;  // safety
            uint4* dst = (uint4*)(binned + (size_t)i * SEGMAXP + gd);
            for (unsigned j = 0; j < rp; j += 4u) {
                uint4 v;
                v.x = (j + 0 < cc) ? stage[ls + j + 0] : SENT;
                v.y = (j + 1 < cc) ? stage[ls + j + 1] : SENT;
                v.z = (j + 2 < cc) ? stage[ls + j + 2] : SENT;
                v.w = (j + 3 < cc) ? stage[ls + j + 3] : SENT;
                dst[j >> 2] = v;
            }
        }
        __syncthreads();
    }

    // ---------------- device-scope barrier ----------------
    if (tid == 0) {
        __threadfence();                         // release: drain stores to device scope
        atomicAdd(done, 1u);
        while (atomicAdd(done, 0u) < (unsigned)gridDim.x)
            __builtin_amdgcn_s_sleep(8);
    }
    __syncthreads();
    __threadfence();                             // acquire: invalidate stale cache
    __syncthreads();

    // ---------------- phase 2: bucket processing ----------------
    unsigned (*ncnt8)[CNODES] = (unsigned (*)[CNODES])shB;   // 8x128
    unsigned* ncnt   = shB + 8 * CNODES;                     // 128
    unsigned* nstart = shB + 8 * CNODES + CNODES;            // 128
    unsigned* scol   = shA;                                  // 7168 <= 8192
    const uint2* qb2 = (const uint2*)qb;

    for (int b = blockIdx.x; b < NC; b += gridDim.x) {
        __syncthreads();
        for (int i = tid; i < 8 * CNODES; i += TPBS) ((unsigned*)ncnt8)[i] = 0u;
        __syncthreads();
        const uint4* seg4 = (const uint4*)(binned) + (size_t)b * SEGMAXP4;
        unsigned m = cursor[b];
        if (m > SEGMAXP) m = SEGMAXP;   // statistically impossible; safety clamp
        unsigned m4 = m >> 2;           // multiple of 4 (PADG=16)
        uint4 it[ITK];
        bool hv[ITK];
        #pragma unroll
        for (int k = 0; k < ITK; ++k) {
            unsigned idx = (unsigned)tid + (unsigned)k * TPBS;
            hv[k] = (idx < m4);
            if (hv[k]) {
                it[k] = seg4[idx];
                if (it[k].x != SENT) atomicAdd(&ncnt8[wid][it[k].x >> 17], 1u);
                if (it[k].y != SENT) atomicAdd(&ncnt8[wid][it[k].y >> 17], 1u);
                if (it[k].z != SENT) atomicAdd(&ncnt8[wid][it[k].z >> 17], 1u);
                if (it[k].w != SENT) atomicAdd(&ncnt8[wid][it[k].w >> 17], 1u);
            }
        }
        __syncthreads();
        // per-node totals + per-wave exclusive prefix
        if (tid < CNODES) {
            unsigned t0 = 0u;
            #pragma unroll
            for (int w = 0; w < 8; ++w) {
                unsigned c = ncnt8[w][tid];
                ncnt8[w][tid] = t0;
                t0 += c;
            }
            ncnt[tid] = t0;
        }
        __syncthreads();
        if (tid < 64) {   // wave 0: exclusive scan of 128 ALIGNED counts, 2/lane
            unsigned c0 = (ncnt[tid * 2] + 3u) & ~3u;
            unsigned c1 = (ncnt[tid * 2 + 1] + 3u) & ~3u;
            unsigned s = c0 + c1;
            unsigned x = s;
            #pragma unroll
            for (int off = 1; off < 64; off <<= 1) {
                unsigned t = __shfl_up(x, off);
                if (tid >= off) x += t;
            }
            unsigned ex = x - s;
            nstart[tid * 2] = ex;
            nstart[tid * 2 + 1] = ex + c0;
        }
        __syncthreads();
        if (tid < CNODES) {   // wave offsets -> absolute cursors
            unsigned ns = nstart[tid];
            #pragma unroll
            for (int w = 0; w < 8; ++w) ncnt8[w][tid] += ns;
        }
        __syncthreads();
        // placement from registers via per-wave cursors
        #pragma unroll
        for (int k = 0; k < ITK; ++k) {
            if (hv[k]) {
                if (it[k].x != SENT) { unsigned rk = atomicAdd(&ncnt8[wid][it[k].x >> 17], 1u); scol[rk] = it[k].x & 0x1FFFFu; }
                if (it[k].y != SENT) { unsigned rk = atomicAdd(&ncnt8[wid][it[k].y >> 17], 1u); scol[rk] = it[k].y & 0x1FFFFu; }
                if (it[k].z != SENT) { unsigned rk = atomicAdd(&ncnt8[wid][it[k].z >> 17], 1u); scol[rk] = it[k].z & 0x1FFFFu; }
                if (it[k].w != SENT) { unsigned rk = atomicAdd(&ncnt8[wid][it[k].w >> 17], 1u); scol[rk] = it[k].w & 0x1FFFFu; }
            }
        }
        // dummy-fill alignment slack (disjoint slots; same phase)
        if (tid < CNODES) {
            unsigned c = ncnt[tid], cp = (c + 3u) & ~3u, st = nstart[tid];
            for (unsigned j = c; j < cp; ++j) scol[st + j] = (unsigned)NN;
        }
        __syncthreads();

        // gather: quad per node, 4 edges per iteration (aligned b128 col reads)
        int nl = tid >> 2;      // node local id 0..127
        int p  = tid & 3;       // feature quad (4 features)
        int n = (b << CSH) + nl;
        unsigned cnt = ncnt[nl], st = nstart[nl];
        const uint2* qp = qb2 + p;
        float a0 = 0.f, a1 = 0.f, a2 = 0.f, a3 = 0.f;
        for (unsigned i = 0; i < cnt; i += 4u) {
            uint4 cc = *(const uint4*)(scol + st + i);
            uint2 vA = qp[(size_t)cc.x * 4];
            uint2 vB = qp[(size_t)cc.y * 4];
            uint2 vC = qp[(size_t)cc.z * 4];
            uint2 vD = qp[(size_t)cc.w * 4];
            a0 += bflo(vA.x); a1 += bfhi(vA.x); a2 += bflo(vA.y); a3 += bfhi(vA.y);
            a0 += bflo(vB.x); a1 += bfhi(vB.x); a2 += bflo(vB.y); a3 += bfhi(vB.y);
            a0 += bflo(vC.x); a1 += bfhi(vC.x); a2 += bflo(vC.y); a3 += bfhi(vC.y);
            a0 += bflo(vD.x); a1 += bfhi(vD.x); a2 += bflo(vD.y); a3 += bfhi(vD.y);
        }
        float ss = 0.f;
        if (n < N) {
            uint2 v = qp[(size_t)n * 4];
            float cf = (float)cnt;
            float d0 = cf * bflo(v.x) - a0, d1 = cf * bfhi(v.x) - a1;
            float d2 = cf * bflo(v.y) - a2, d3 = cf * bfhi(v.y) - a3;
            ss = d0 * d0 + d1 * d1 + d2 * d2 + d3 * d3;
        }
        // quad reduce (features) then wave reduce (nodes)
        ss += __shfl_xor(ss, 1);
        ss += __shfl_xor(ss, 2);
        float bss = 0.f;
        if (p == 0 && n < N) {
            float c1f = (cnt > 1u) ? (float)cnt : 1.f;
            bss = ss / (c1f * c1f);
        }
        #pragma unroll
        for (int mm = 4; mm < 64; mm <<= 1) bss += __shfl_xor(bss, mm);
        if (lane == 0) wred[wid] = bss;
        __syncthreads();
        if (tid == 0) {
            float acc = 0.f;
            #pragma unroll
            for (int w = 0; w < 8; ++w) acc += wred[w];
            atomicAdd(out, acc * (1.0f / (float)NN));
        }
    }
}

extern "C" void kernel_launch(void* const* d_in, const int* in_sizes, int n_in,
                              void* d_out, int out_size, void* d_ws, size_t ws_size,
                              hipStream_t stream) {
    const float* pred = (const float*)d_in[0];
    const float* inp  = (const float*)d_in[1];
    const int*   eidx = (const int*)d_in[2];

    const int N = NN;
    const int E = in_sizes[2] / 2;
    const int* row = eidx;
    const int* col = eidx + E;

    // ws layout
    size_t off = 0;
    auto alloc = [&](size_t bytes) { void* p = (char*)d_ws + off; off = (off + bytes + 511) & ~(size_t)511; return p; };
    uint4*    qb     = (uint4*)alloc((size_t)(N + 1) * 32);   // bf16 q + dummy node NN
    unsigned* cursor = (unsigned*)alloc((NC + 16) * sizeof(unsigned));  // +done counter
    unsigned* binned = (unsigned*)alloc((size_t)NC * SEGMAXP * sizeof(unsigned));
    unsigned* done   = cursor + NC;

    hipMemsetAsync(cursor, 0, (NC + 16) * sizeof(unsigned), stream);

    int n8 = N * 16 / 8;   // 200000
    int E4 = E >> 2;
    int nsc = (E4 + TILE4 - 1) / TILE4;   // 391 for E=3.2M; all-resident (<= 768)
    k_fused<<<nsc, TPBS, 0, stream>>>((const float4*)pred, (const float4*)inp, qb,
                                      (const int4*)row, (const int4*)col, row, col,
                                      cursor, binned, done, (float*)d_out, E, n8, N);
}

// Round 16
// 85.299 us; speedup vs baseline: 1.8507x; 1.8507x over previous
//
#include <hip/hip_runtime.h>

#define NN 100000
#define CSH 7                        // 128 nodes per bucket
#define CNODES 128
#define NC ((NN + CNODES - 1) / CNODES)      // 782 buckets
#define TPBS 512                     // scat1 block
#define TPBB 512                     // bucket block (= CNODES quads)
#define EPQ 2                        // int4 loads per thread in scat1
#define TILE4 (TPBS * EPQ)           // 1024 int4 = 4096 edges per tile
#define TILEE (TILE4 * 4)            // 4096
#define PADG 8u                      // pad runs to 8 edges = 32 B (uint4-aligned)
#define SEGMAXP 7680                 // padded per-bucket capacity (mean ~6725, ~13 sigma)
#define SEGMAXP4 (SEGMAXP / 4)       // 1920 <= ITK*TPBB = 2048
#define ITK 4                        // uint4 items per thread in k_bucket
#define SENT 0xFFFFFFFFu

// ---- bf16 pack/unpack helpers (RNE) ----
__device__ __forceinline__ unsigned f2bf(float f) {
    unsigned u = __float_as_uint(f);
    return (u + 0x7FFFu + ((u >> 16) & 1u)) >> 16;
}
__device__ __forceinline__ unsigned pk(float lo, float hi) {
    return f2bf(lo) | (f2bf(hi) << 16);
}
__device__ __forceinline__ float bflo(unsigned v) { return __uint_as_float(v << 16); }
__device__ __forceinline__ float bfhi(unsigned v) { return __uint_as_float(v & 0xFFFF0000u); }

// one block per 4096-edge tile: fused q-pack slice + LDS multisplit
// (hist -> hierarchical scan -> rank-scatter into LDS stage), then flush
// per-bucket runs padded to 8 edges with full 16 B uint4 stores.
// payload = (row&127)<<17 | col; cursor[b] ends as padded segment count.
__global__ __launch_bounds__(TPBS) void k_scat1(const float4* __restrict__ pred,
                        const float4* __restrict__ inp, uint4* __restrict__ qb,
                        const int4* __restrict__ row4, const int4* __restrict__ col4,
                        const int* __restrict__ row, const int* __restrict__ col,
                        unsigned* __restrict__ cursor, unsigned* __restrict__ binned,
                        float* __restrict__ out, int E, int n8) {
    __shared__ unsigned lcnt[NC], lofs[NC], lpos[NC], gdst[NC];
    __shared__ unsigned stage[TILEE];    // 16 KB
    __shared__ unsigned wtot[8], wofs[8];
    int tid = threadIdx.x;
    int lane = tid & 63, wid = tid >> 6;
    int E4 = E >> 2;
    long long base4 = (long long)blockIdx.x * TILE4;
    bool lastblk = (blockIdx.x == gridDim.x - 1);

    if (blockIdx.x == 0 && tid == 0) {   // out + dummy-q init (bucket runs later)
        *out = 0.f;
        qb[2 * NN]     = make_uint4(0u, 0u, 0u, 0u);
        qb[2 * NN + 1] = make_uint4(0u, 0u, 0u, 0u);
    }

    // fused q-pack: this block's slice
    for (int i = blockIdx.x * TPBS + tid; i < n8; i += gridDim.x * TPBS) {
        float4 a0 = pred[2 * i], a1 = pred[2 * i + 1];
        float4 b0 = inp[2 * i],  b1 = inp[2 * i + 1];
        uint4 o;
        o.x = pk(a0.x - b0.x, a0.y - b0.y);
        o.y = pk(a0.z - b0.z, a0.w - b0.w);
        o.z = pk(a1.x - b1.x, a1.y - b1.y);
        o.w = pk(a1.z - b1.z, a1.w - b1.w);
        qb[i] = o;
    }

    for (int i = tid; i < NC; i += TPBS) { lcnt[i] = 0u; lpos[i] = 0u; }
    __syncthreads();
    int4 r[EPQ], c[EPQ];
    bool val[EPQ];
    #pragma unroll
    for (int j = 0; j < EPQ; ++j) {
        long long i4 = base4 + (long long)j * TPBS + tid;
        val[j] = (i4 < E4);
        if (val[j]) {
            r[j] = row4[i4]; c[j] = col4[i4];
            atomicAdd(&lcnt[((unsigned)r[j].x) >> CSH], 1u);
            atomicAdd(&lcnt[((unsigned)r[j].y) >> CSH], 1u);
            atomicAdd(&lcnt[((unsigned)r[j].z) >> CSH], 1u);
            atomicAdd(&lcnt[((unsigned)r[j].w) >> CSH], 1u);
        }
    }
    int rt = 0, ct_ = 0;
    bool tval = lastblk && tid < (E & 3);
    if (tval) {
        int e = (E & ~3) + tid;
        rt = row[e]; ct_ = col[e];
        atomicAdd(&lcnt[((unsigned)rt) >> CSH], 1u);
    }
    __syncthreads();
    // hierarchical exclusive scan of lcnt (2 buckets per thread)
    unsigned v0 = (2 * tid     < NC) ? lcnt[2 * tid]     : 0u;
    unsigned v1 = (2 * tid + 1 < NC) ? lcnt[2 * tid + 1] : 0u;
    unsigned s = v0 + v1;
    unsigned x = s;
    #pragma unroll
    for (int off = 1; off < 64; off <<= 1) {
        unsigned t = __shfl_up(x, off);
        if (lane >= off) x += t;
    }
    if (lane == 63) wtot[wid] = x;
    __syncthreads();
    if (tid < 8) {
        unsigned wv = wtot[tid], wx = wv;
        #pragma unroll
        for (int off = 1; off < 8; off <<= 1) {
            unsigned t = __shfl_up(wx, off);
            if (tid >= off) wx += t;
        }
        wofs[tid] = wx - wv;
    }
    __syncthreads();
    unsigned ex = x - s + wofs[wid];
    if (2 * tid < NC) {
        lofs[2 * tid] = ex;
        unsigned rp = (v0 + PADG - 1u) & ~(PADG - 1u);
        gdst[2 * tid] = rp ? atomicAdd(&cursor[2 * tid], rp) : 0u;
    }
    if (2 * tid + 1 < NC) {
        lofs[2 * tid + 1] = ex + v0;
        unsigned rp = (v1 + PADG - 1u) & ~(PADG - 1u);
        gdst[2 * tid + 1] = rp ? atomicAdd(&cursor[2 * tid + 1], rp) : 0u;
    }
    __syncthreads();
    // rank-scatter payloads into LDS stage (contiguous per bucket)
    #pragma unroll
    for (int j = 0; j < EPQ; ++j) {
        if (val[j]) {
            int rr[4] = {r[j].x, r[j].y, r[j].z, r[j].w};
            int cc4[4] = {c[j].x, c[j].y, c[j].z, c[j].w};
            #pragma unroll
            for (int k = 0; k < 4; ++k) {
                unsigned ru = (unsigned)rr[k];
                unsigned b = ru >> CSH;
                unsigned pos = lofs[b] + atomicAdd(&lpos[b], 1u);
                stage[pos] = ((ru & (CNODES - 1u)) << 17) | (unsigned)cc4[k];
            }
        }
    }
    if (tval) {
        unsigned ru = (unsigned)rt;
        unsigned b = ru >> CSH;
        unsigned pos = lofs[b] + atomicAdd(&lpos[b], 1u);
        stage[pos] = ((ru & (CNODES - 1u)) << 17) | (unsigned)ct_;
    }
    __syncthreads();
    // flush: only full 16 B aligned stores; sentinel-pad to the 8-edge boundary
    for (int i = tid; i < NC; i += TPBS) {
        unsigned cc = lcnt[i];
        unsigned rp = (cc + PADG - 1u) & ~(PADG - 1u);
        unsigned ls = lofs[i];
        unsigned gd = gdst[i];
        if (gd + rp > SEGMAXP) rp = (gd < SEGMAXP) ? (SEGMAXP - gd) : 0u;  // safety
        uint4* dst = (uint4*)(binned + (size_t)i * SEGMAXP + gd);
        for (unsigned j = 0; j < rp; j += 4u) {
            uint4 v;
            v.x = (j + 0 < cc) ? stage[ls + j + 0] : SENT;
            v.y = (j + 1 < cc) ? stage[ls + j + 1] : SENT;
            v.z = (j + 2 < cc) ? stage[ls + j + 2] : SENT;
            v.w = (j + 3 < cc) ? stage[ls + j + 3] : SENT;
            dst[j >> 2] = v;
        }
    }
}

// one 512-thread block per 128-node bucket: single uint4 read of the segment
// into registers; per-wave split histogram + register-sourced placement into
// 16 B-ALIGNED per-node runs (slack = dummy col NN -> q=0); then one 4-lane
// quad per node walks its list 4 edges at a time (aligned b128 col reads,
// 4 independent 8 B gathers, no tail predicates); finalize and reduce to out.
__global__ __launch_bounds__(TPBB) void k_bucket(const uint2* __restrict__ qb2,
                         const uint4* __restrict__ binned4,
                         const unsigned* __restrict__ cursor,
                         float* __restrict__ out, int N) {
    __shared__ unsigned ncnt8[8][CNODES];   // per-wave counters -> cursors
    __shared__ unsigned ncnt[CNODES], nstart[CNODES];
    __shared__ unsigned scol[SEGMAXP];      // 30 KB
    __shared__ float wred[8];
    int tid = threadIdx.x, b = blockIdx.x;
    int lane = tid & 63, wid = tid >> 6;
    for (int i = tid; i < 8 * CNODES; i += TPBB) ((unsigned*)ncnt8)[i] = 0u;
    __syncthreads();
    const uint4* seg4 = binned4 + (size_t)b * SEGMAXP4;
    unsigned m = cursor[b];
    if (m > SEGMAXP) m = SEGMAXP;   // statistically impossible; safety clamp
    unsigned m4 = m >> 2;           // multiple of 2 (PADG=8 -> 2 uint4)
    uint4 it[ITK];
    bool hv[ITK];
    #pragma unroll
    for (int k = 0; k < ITK; ++k) {
        unsigned idx = (unsigned)tid + (unsigned)k * TPBB;
        hv[k] = (idx < m4);
        if (hv[k]) {
            it[k] = seg4[idx];
            if (it[k].x != SENT) atomicAdd(&ncnt8[wid][it[k].x >> 17], 1u);
            if (it[k].y != SENT) atomicAdd(&ncnt8[wid][it[k].y >> 17], 1u);
            if (it[k].z != SENT) atomicAdd(&ncnt8[wid][it[k].z >> 17], 1u);
            if (it[k].w != SENT) atomicAdd(&ncnt8[wid][it[k].w >> 17], 1u);
        }
    }
    __syncthreads();
    // per-node: total count + exclusive per-wave prefix (counts -> wave offsets)
    if (tid < CNODES) {
        unsigned t0 = 0u;
        #pragma unroll
        for (int w = 0; w < 8; ++w) {
            unsigned c = ncnt8[w][tid];
            ncnt8[w][tid] = t0;
            t0 += c;
        }
        ncnt[tid] = t0;
    }
    __syncthreads();
    if (tid < 64) {   // wave 0: exclusive scan of 128 ALIGNED counts, 2 per lane
        unsigned c0 = (ncnt[tid * 2] + 3u) & ~3u;
        unsigned c1 = (ncnt[tid * 2 + 1] + 3u) & ~3u;
        unsigned s = c0 + c1;
        unsigned x = s;
        #pragma unroll
        for (int off = 1; off < 64; off <<= 1) {
            unsigned t = __shfl_up(x, off);
            if (tid >= off) x += t;
        }
        unsigned ex = x - s;
        nstart[tid * 2] = ex;
        nstart[tid * 2 + 1] = ex + c0;
    }
    __syncthreads();
    if (tid < CNODES) {   // wave offsets -> absolute cursors
        unsigned ns = nstart[tid];
        #pragma unroll
        for (int w = 0; w < 8; ++w) ncnt8[w][tid] += ns;
    }
    __syncthreads();
    // placement from registers via per-wave cursors
    #pragma unroll
    for (int k = 0; k < ITK; ++k) {
        if (hv[k]) {
            if (it[k].x != SENT) { unsigned rk = atomicAdd(&ncnt8[wid][it[k].x >> 17], 1u); scol[rk] = it[k].x & 0x1FFFFu; }
            if (it[k].y != SENT) { unsigned rk = atomicAdd(&ncnt8[wid][it[k].y >> 17], 1u); scol[rk] = it[k].y & 0x1FFFFu; }
            if (it[k].z != SENT) { unsigned rk = atomicAdd(&ncnt8[wid][it[k].z >> 17], 1u); scol[rk] = it[k].z & 0x1FFFFu; }
            if (it[k].w != SENT) { unsigned rk = atomicAdd(&ncnt8[wid][it[k].w >> 17], 1u); scol[rk] = it[k].w & 0x1FFFFu; }
        }
    }
    // dummy-fill alignment slack (disjoint slots; same phase as placement)
    if (tid < CNODES) {
        unsigned c = ncnt[tid], cp = (c + 3u) & ~3u, st = nstart[tid];
        for (unsigned j = c; j < cp; ++j) scol[st + j] = (unsigned)NN;
    }
    __syncthreads();

    // gather: quad per node, 4 edges per iteration (aligned b128 col reads)
    int nl = tid >> 2;      // node local id 0..127
    int p  = tid & 3;       // feature quad (4 features)
    int n = (b << CSH) + nl;
    unsigned cnt = ncnt[nl], st = nstart[nl];
    const uint2* qp = qb2 + p;
    float a0 = 0.f, a1 = 0.f, a2 = 0.f, a3 = 0.f;
    for (unsigned i = 0; i < cnt; i += 4u) {
        uint4 cc = *(const uint4*)(scol + st + i);
        uint2 vA = qp[(size_t)cc.x * 4];
        uint2 vB = qp[(size_t)cc.y * 4];
        uint2 vC = qp[(size_t)cc.z * 4];
        uint2 vD = qp[(size_t)cc.w * 4];
        a0 += bflo(vA.x); a1 += bfhi(vA.x); a2 += bflo(vA.y); a3 += bfhi(vA.y);
        a0 += bflo(vB.x); a1 += bfhi(vB.x); a2 += bflo(vB.y); a3 += bfhi(vB.y);
        a0 += bflo(vC.x); a1 += bfhi(vC.x); a2 += bflo(vC.y); a3 += bfhi(vC.y);
        a0 += bflo(vD.x); a1 += bfhi(vD.x); a2 += bflo(vD.y); a3 += bfhi(vD.y);
    }
    float ss = 0.f;
    if (n < N) {
        uint2 v = qp[(size_t)n * 4];
        float cf = (float)cnt;
        float d0 = cf * bflo(v.x) - a0, d1 = cf * bfhi(v.x) - a1;
        float d2 = cf * bflo(v.y) - a2, d3 = cf * bfhi(v.y) - a3;
        ss = d0 * d0 + d1 * d1 + d2 * d2 + d3 * d3;
    }
    // quad reduce (features) then wave reduce (nodes)
    ss += __shfl_xor(ss, 1);
    ss += __shfl_xor(ss, 2);
    float bss = 0.f;
    if (p == 0 && n < N) {
        float c1f = (cnt > 1u) ? (float)cnt : 1.f;
        bss = ss / (c1f * c1f);
    }
    #pragma unroll
    for (int mm = 4; mm < 64; mm <<= 1) bss += __shfl_xor(bss, mm);
    if (lane == 0) wred[wid] = bss;
    __syncthreads();
    if (tid == 0) {
        float acc = 0.f;
        #pragma unroll
        for (int w = 0; w < 8; ++w) acc += wred[w];
        atomicAdd(out, acc * (1.0f / (float)NN));
    }
}

extern "C" void kernel_launch(void* const* d_in, const int* in_sizes, int n_in,
                              void* d_out, int out_size, void* d_ws, size_t ws_size,
                              hipStream_t stream) {
    const float* pred = (const float*)d_in[0];
    const float* inp  = (const float*)d_in[1];
    const int*   eidx = (const int*)d_in[2];

    const int N = NN;
    const int E = in_sizes[2] / 2;
    const int* row = eidx;
    const int* col = eidx + E;

    // ws layout
    size_t off = 0;
    auto alloc = [&](size_t bytes) { void* p = (char*)d_ws + off; off = (off + bytes + 511) & ~(size_t)511; return p; };
    uint4*    qb     = (uint4*)alloc((size_t)(N + 1) * 32);   // bf16 q + dummy node NN
    unsigned* cursor = (unsigned*)alloc(NC * sizeof(unsigned));
    unsigned* binned = (unsigned*)alloc((size_t)NC * SEGMAXP * sizeof(unsigned));

    hipMemsetAsync(cursor, 0, NC * sizeof(unsigned), stream);

    int n8 = N * 16 / 8;   // 200000
    int E4 = E >> 2;
    int nsc = (E4 + TILE4 - 1) / TILE4;   // 782 for E=3.2M -> ~3 blocks/CU
    k_scat1<<<nsc, TPBS, 0, stream>>>((const float4*)pred, (const float4*)inp, qb,
                                      (const int4*)row, (const int4*)col, row, col,
                                      cursor, binned, (float*)d_out, E, n8);

    k_bucket<<<NC, TPBB, 0, stream>>>((const uint2*)qb, (const uint4*)binned, cursor,
                                      (float*)d_out, N);
}

// Round 17
// 61.339 us; speedup vs baseline: 2.5736x; 1.3906x over previous
//
#include <hip/hip_runtime.h>

#define NN 100000
#define CSH 7                        // 128 nodes per bucket
#define CNODES 128
#define NC ((NN + CNODES - 1) / CNODES)      // 782 buckets
#define TPBS 1024                    // scat1 block (16 waves)
#define TPBB 512                     // bucket block (= CNODES quads)
#define EPQ 2                        // int4 loads per thread in scat1
#define TILE4 (TPBS * EPQ)           // 2048 int4 = 8192 edges per tile
#define TILEE (TILE4 * 4)            // 8192
#define PADG 16u                     // pad runs to 16 edges = 64 B line
#define SEGMAXP 7168                 // padded per-bucket capacity (mean ~6500, ~10 sigma)
#define SEGMAXP4 (SEGMAXP / 4)
#define ITK 4                        // uint4 items per thread in k_bucket
#define SENT 0xFFFFFFFFu

// ---- bf16 pack/unpack helpers (RNE) ----
__device__ __forceinline__ unsigned f2bf(float f) {
    unsigned u = __float_as_uint(f);
    return (u + 0x7FFFu + ((u >> 16) & 1u)) >> 16;
}
__device__ __forceinline__ unsigned pk(float lo, float hi) {
    return f2bf(lo) | (f2bf(hi) << 16);
}
__device__ __forceinline__ float bflo(unsigned v) { return __uint_as_float(v << 16); }
__device__ __forceinline__ float bfhi(unsigned v) { return __uint_as_float(v & 0xFFFF0000u); }

// one 1024-thread block per 8192-edge tile: fused q-pack slice + LDS multisplit
// (hist -> hierarchical scan -> rank-scatter into LDS stage), then flush
// per-bucket runs padded to 16 edges with full 16 B uint4 stores.
// payload = (row&127)<<17 | col; cursor[b] ends as padded segment count.
__global__ __launch_bounds__(TPBS) void k_scat1(const float4* __restrict__ pred,
                        const float4* __restrict__ inp, uint4* __restrict__ qb,
                        const int4* __restrict__ row4, const int4* __restrict__ col4,
                        const int* __restrict__ row, const int* __restrict__ col,
                        unsigned* __restrict__ cursor, unsigned* __restrict__ binned,
                        float* __restrict__ out, int E, int n8) {
    __shared__ unsigned lcnt[NC], lofs[NC], lpos[NC], gdst[NC];
    __shared__ unsigned stage[TILEE];    // 32 KB
    __shared__ unsigned wtot[16], wofs[16];
    int tid = threadIdx.x;
    int lane = tid & 63, wid = tid >> 6;   // wid 0..15
    int E4 = E >> 2;
    long long base4 = (long long)blockIdx.x * TILE4;
    bool lastblk = (blockIdx.x == gridDim.x - 1);

    if (blockIdx.x == 0 && tid == 0) {   // out + dummy-q init (bucket runs later)
        *out = 0.f;
        qb[2 * NN]     = make_uint4(0u, 0u, 0u, 0u);
        qb[2 * NN + 1] = make_uint4(0u, 0u, 0u, 0u);
    }

    // fused q-pack: this block's slice
    for (int i = blockIdx.x * TPBS + tid; i < n8; i += gridDim.x * TPBS) {
        float4 a0 = pred[2 * i], a1 = pred[2 * i + 1];
        float4 b0 = inp[2 * i],  b1 = inp[2 * i + 1];
        uint4 o;
        o.x = pk(a0.x - b0.x, a0.y - b0.y);
        o.y = pk(a0.z - b0.z, a0.w - b0.w);
        o.z = pk(a1.x - b1.x, a1.y - b1.y);
        o.w = pk(a1.z - b1.z, a1.w - b1.w);
        qb[i] = o;
    }

    for (int i = tid; i < NC; i += TPBS) { lcnt[i] = 0u; lpos[i] = 0u; }
    __syncthreads();
    int4 r[EPQ], c[EPQ];
    bool val[EPQ];
    #pragma unroll
    for (int j = 0; j < EPQ; ++j) {
        long long i4 = base4 + (long long)j * TPBS + tid;
        val[j] = (i4 < E4);
        if (val[j]) {
            r[j] = row4[i4]; c[j] = col4[i4];
            atomicAdd(&lcnt[((unsigned)r[j].x) >> CSH], 1u);
            atomicAdd(&lcnt[((unsigned)r[j].y) >> CSH], 1u);
            atomicAdd(&lcnt[((unsigned)r[j].z) >> CSH], 1u);
            atomicAdd(&lcnt[((unsigned)r[j].w) >> CSH], 1u);
        }
    }
    int rt = 0, ct_ = 0;
    bool tval = lastblk && tid < (E & 3);
    if (tval) {
        int e = (E & ~3) + tid;
        rt = row[e]; ct_ = col[e];
        atomicAdd(&lcnt[((unsigned)rt) >> CSH], 1u);
    }
    __syncthreads();
    // hierarchical exclusive scan of lcnt (1 bucket per thread; NC <= TPBS)
    unsigned v0 = (tid < NC) ? lcnt[tid] : 0u;
    unsigned x = v0;
    #pragma unroll
    for (int off = 1; off < 64; off <<= 1) {
        unsigned t = __shfl_up(x, off);
        if (lane >= off) x += t;
    }
    if (lane == 63) wtot[wid] = x;
    __syncthreads();
    if (tid < 16) {
        unsigned wv = wtot[tid], wx = wv;
        #pragma unroll
        for (int off = 1; off < 16; off <<= 1) {
            unsigned t = __shfl_up(wx, off);
            if (tid >= off) wx += t;
        }
        wofs[tid] = wx - wv;
    }
    __syncthreads();
    if (tid < NC) {
        unsigned ex = x - v0 + wofs[wid];
        lofs[tid] = ex;
        unsigned rp = (v0 + PADG - 1u) & ~(PADG - 1u);
        gdst[tid] = rp ? atomicAdd(&cursor[tid], rp) : 0u;
    }
    __syncthreads();
    // rank-scatter payloads into LDS stage (contiguous per bucket)
    #pragma unroll
    for (int j = 0; j < EPQ; ++j) {
        if (val[j]) {
            int rr[4] = {r[j].x, r[j].y, r[j].z, r[j].w};
            int cc4[4] = {c[j].x, c[j].y, c[j].z, c[j].w};
            #pragma unroll
            for (int k = 0; k < 4; ++k) {
                unsigned ru = (unsigned)rr[k];
                unsigned b = ru >> CSH;
                unsigned pos = lofs[b] + atomicAdd(&lpos[b], 1u);
                stage[pos] = ((ru & (CNODES - 1u)) << 17) | (unsigned)cc4[k];
            }
        }
    }
    if (tval) {
        unsigned ru = (unsigned)rt;
        unsigned b = ru >> CSH;
        unsigned pos = lofs[b] + atomicAdd(&lpos[b], 1u);
        stage[pos] = ((ru & (CNODES - 1u)) << 17) | (unsigned)ct_;
    }
    __syncthreads();
    // flush: only full 16 B aligned stores; sentinel-pad to the 16-edge boundary
    if (tid < NC) {
        unsigned cc = lcnt[tid];
        unsigned rp = (cc + PADG - 1u) & ~(PADG - 1u);
        unsigned ls = lofs[tid];
        unsigned gd = gdst[tid];
        if (gd + rp > SEGMAXP) rp = (gd < SEGMAXP) ? (SEGMAXP - gd) : 0u;  // safety
        uint4* dst = (uint4*)(binned + (size_t)tid * SEGMAXP + gd);
        for (unsigned j = 0; j < rp; j += 4u) {
            uint4 v;
            v.x = (j + 0 < cc) ? stage[ls + j + 0] : SENT;
            v.y = (j + 1 < cc) ? stage[ls + j + 1] : SENT;
            v.z = (j + 2 < cc) ? stage[ls + j + 2] : SENT;
            v.w = (j + 3 < cc) ? stage[ls + j + 3] : SENT;
            dst[j >> 2] = v;
        }
    }
}

// one 512-thread block per 128-node bucket: single uint4 read of the segment
// into registers; per-wave split histogram + register-sourced placement into
// 16 B-ALIGNED per-node runs (slack = dummy col NN -> q=0); then one 4-lane
// quad per node walks its list 4 edges at a time (aligned b128 col reads,
// 4 independent 8 B gathers, no tail predicates); finalize and reduce to out.
__global__ __launch_bounds__(TPBB) void k_bucket(const uint2* __restrict__ qb2,
                         const uint4* __restrict__ binned4,
                         const unsigned* __restrict__ cursor,
                         float* __restrict__ out, int N) {
    __shared__ unsigned ncnt8[8][CNODES];   // per-wave counters -> cursors
    __shared__ unsigned ncnt[CNODES], nstart[CNODES];
    __shared__ unsigned scol[SEGMAXP];      // 28 KB
    __shared__ float wred[8];
    int tid = threadIdx.x, b = blockIdx.x;
    int lane = tid & 63, wid = tid >> 6;
    for (int i = tid; i < 8 * CNODES; i += TPBB) ((unsigned*)ncnt8)[i] = 0u;
    __syncthreads();
    const uint4* seg4 = binned4 + (size_t)b * SEGMAXP4;
    unsigned m = cursor[b];
    if (m > SEGMAXP) m = SEGMAXP;   // statistically impossible; safety clamp
    unsigned m4 = m >> 2;           // multiple of 4 (PADG=16)
    uint4 it[ITK];
    bool hv[ITK];
    #pragma unroll
    for (int k = 0; k < ITK; ++k) {
        unsigned idx = (unsigned)tid + (unsigned)k * TPBB;
        hv[k] = (idx < m4);
        if (hv[k]) {
            it[k] = seg4[idx];
            if (it[k].x != SENT) atomicAdd(&ncnt8[wid][it[k].x >> 17], 1u);
            if (it[k].y != SENT) atomicAdd(&ncnt8[wid][it[k].y >> 17], 1u);
            if (it[k].z != SENT) atomicAdd(&ncnt8[wid][it[k].z >> 17], 1u);
            if (it[k].w != SENT) atomicAdd(&ncnt8[wid][it[k].w >> 17], 1u);
        }
    }
    __syncthreads();
    // per-node: total count + exclusive per-wave prefix (counts -> wave offsets)
    if (tid < CNODES) {
        unsigned t0 = 0u;
        #pragma unroll
        for (int w = 0; w < 8; ++w) {
            unsigned c = ncnt8[w][tid];
            ncnt8[w][tid] = t0;
            t0 += c;
        }
        ncnt[tid] = t0;
    }
    __syncthreads();
    if (tid < 64) {   // wave 0: exclusive scan of 128 ALIGNED counts, 2 per lane
        unsigned c0 = (ncnt[tid * 2] + 3u) & ~3u;
        unsigned c1 = (ncnt[tid * 2 + 1] + 3u) & ~3u;
        unsigned s = c0 + c1;
        unsigned x = s;
        #pragma unroll
        for (int off = 1; off < 64; off <<= 1) {
            unsigned t = __shfl_up(x, off);
            if (tid >= off) x += t;
        }
        unsigned ex = x - s;
        nstart[tid * 2] = ex;
        nstart[tid * 2 + 1] = ex + c0;
    }
    __syncthreads();
    if (tid < CNODES) {   // wave offsets -> absolute cursors
        unsigned ns = nstart[tid];
        #pragma unroll
        for (int w = 0; w < 8; ++w) ncnt8[w][tid] += ns;
    }
    __syncthreads();
    // placement from registers via per-wave cursors
    #pragma unroll
    for (int k = 0; k < ITK; ++k) {
        if (hv[k]) {
            if (it[k].x != SENT) { unsigned rk = atomicAdd(&ncnt8[wid][it[k].x >> 17], 1u); scol[rk] = it[k].x & 0x1FFFFu; }
            if (it[k].y != SENT) { unsigned rk = atomicAdd(&ncnt8[wid][it[k].y >> 17], 1u); scol[rk] = it[k].y & 0x1FFFFu; }
            if (it[k].z != SENT) { unsigned rk = atomicAdd(&ncnt8[wid][it[k].z >> 17], 1u); scol[rk] = it[k].z & 0x1FFFFu; }
            if (it[k].w != SENT) { unsigned rk = atomicAdd(&ncnt8[wid][it[k].w >> 17], 1u); scol[rk] = it[k].w & 0x1FFFFu; }
        }
    }
    // dummy-fill alignment slack (disjoint slots; same phase as placement)
    if (tid < CNODES) {
        unsigned c = ncnt[tid], cp = (c + 3u) & ~3u, st = nstart[tid];
        for (unsigned j = c; j < cp; ++j) scol[st + j] = (unsigned)NN;
    }
    __syncthreads();

    // gather: quad per node, 4 edges per iteration (aligned b128 col reads)
    int nl = tid >> 2;      // node local id 0..127
    int p  = tid & 3;       // feature quad (4 features)
    int n = (b << CSH) + nl;
    unsigned cnt = ncnt[nl], st = nstart[nl];
    const uint2* qp = qb2 + p;
    float a0 = 0.f, a1 = 0.f, a2 = 0.f, a3 = 0.f;
    for (unsigned i = 0; i < cnt; i += 4u) {
        uint4 cc = *(const uint4*)(scol + st + i);
        uint2 vA = qp[(size_t)cc.x * 4];
        uint2 vB = qp[(size_t)cc.y * 4];
        uint2 vC = qp[(size_t)cc.z * 4];
        uint2 vD = qp[(size_t)cc.w * 4];
        a0 += bflo(vA.x); a1 += bfhi(vA.x); a2 += bflo(vA.y); a3 += bfhi(vA.y);
        a0 += bflo(vB.x); a1 += bfhi(vB.x); a2 += bflo(vB.y); a3 += bfhi(vB.y);
        a0 += bflo(vC.x); a1 += bfhi(vC.x); a2 += bflo(vC.y); a3 += bfhi(vC.y);
        a0 += bflo(vD.x); a1 += bfhi(vD.x); a2 += bflo(vD.y); a3 += bfhi(vD.y);
    }
    float ss = 0.f;
    if (n < N) {
        uint2 v = qp[(size_t)n * 4];
        float cf = (float)cnt;
        float d0 = cf * bflo(v.x) - a0, d1 = cf * bfhi(v.x) - a1;
        float d2 = cf * bflo(v.y) - a2, d3 = cf * bfhi(v.y) - a3;
        ss = d0 * d0 + d1 * d1 + d2 * d2 + d3 * d3;
    }
    // quad reduce (features) then wave reduce (nodes)
    ss += __shfl_xor(ss, 1);
    ss += __shfl_xor(ss, 2);
    float bss = 0.f;
    if (p == 0 && n < N) {
        float c1f = (cnt > 1u) ? (float)cnt : 1.f;
        bss = ss / (c1f * c1f);
    }
    #pragma unroll
    for (int mm = 4; mm < 64; mm <<= 1) bss += __shfl_xor(bss, mm);
    if (lane == 0) wred[wid] = bss;
    __syncthreads();
    if (tid == 0) {
        float acc = 0.f;
        #pragma unroll
        for (int w = 0; w < 8; ++w) acc += wred[w];
        atomicAdd(out, acc * (1.0f / (float)NN));
    }
}

extern "C" void kernel_launch(void* const* d_in, const int* in_sizes, int n_in,
                              void* d_out, int out_size, void* d_ws, size_t ws_size,
                              hipStream_t stream) {
    const float* pred = (const float*)d_in[0];
    const float* inp  = (const float*)d_in[1];
    const int*   eidx = (const int*)d_in[2];

    const int N = NN;
    const int E = in_sizes[2] / 2;
    const int* row = eidx;
    const int* col = eidx + E;

    // ws layout
    size_t off = 0;
    auto alloc = [&](size_t bytes) { void* p = (char*)d_ws + off; off = (off + bytes + 511) & ~(size_t)511; return p; };
    uint4*    qb     = (uint4*)alloc((size_t)(N + 1) * 32);   // bf16 q + dummy node NN
    unsigned* cursor = (unsigned*)alloc(NC * sizeof(unsigned));
    unsigned* binned = (unsigned*)alloc((size_t)NC * SEGMAXP * sizeof(unsigned));

    hipMemsetAsync(cursor, 0, NC * sizeof(unsigned), stream);

    int n8 = N * 16 / 8;   // 200000
    int E4 = E >> 2;
    int nsc = (E4 + TILE4 - 1) / TILE4;   // 391 for E=3.2M
    k_scat1<<<nsc, TPBS, 0, stream>>>((const float4*)pred, (const float4*)inp, qb,
                                      (const int4*)row, (const int4*)col, row, col,
                                      cursor, binned, (float*)d_out, E, n8);

    k_bucket<<<NC, TPBB, 0, stream>>>((const uint2*)qb, (const uint4*)binned, cursor,
                                      (float*)d_out, N);
}